// Round 3
// baseline (737.192 us; speedup 1.0000x reference)
//
#include <hip/hip_runtime.h>
#include <math.h>

// SVPF step: B=8, N=2048, D=4, fp32.  3 SVGD iterations.
// log_weight output channel is exactly -log(2048) (log_post cancels).
//
// R3 changes vs R2 (diagnosis: everything is L1/L2-resident; LDS staging was
// capping occupancy at 2-3 blocks/CU on latency-bound kernels):
//  - k_grad / k_stein: NO LDS at all; x/g/ap read from global (L1-resident,
//    same-address group loads broadcast).  16 threads/particle, 1024 blocks.
//  - k_hist: only the 16KB histogram in LDS; xj streamed from global.
//    1024 blocks (8 batch x 8 i-tile x 16 k-tile).
//  - scans fused into hist kernels via per-batch last-block pattern
//    (threadfence + counter; agent-scope atomic loads to bypass stale L1).
//  - stein uses diff-form repulsion  rep = (2/h) * sum_j e_ij (x_i - x_j)
//    (drops the S0 accumulator; better conditioned).
//  - k_out fused into k_stein<2>; stepb not read on iter 0, not written on
//    iter 2; x not written on iter 2.
//  - 13 launches total (was 20).
//
// ws layout (floats):
//   xA[65536] xB[65536] g[65536] step[65536] ap[65536]
//   hpar[32] state[32 ints] hist0[8*4096 ints] hist1[8*4096 ints] ctr[64 ints]

#define NPART 2048
#define KRANK 2097151               // (2048*2048-1)/2, lower-median rank
#define LOGN_F 7.6246189861593985f  // log(2048)
#define A_C 0.9f

// ---------- init: x0 = A*prev + noise; ap = A*prev; zero hists + counters
__global__ __launch_bounds__(256) void k_init(const float* __restrict__ prev,
                                              const float* __restrict__ noise,
                                              float* __restrict__ x0,
                                              float* __restrict__ apb,
                                              int* __restrict__ hists,
                                              int* __restrict__ ctrs) {
  int idx = blockIdx.x * 256 + threadIdx.x;   // 0..16383 (B*N)
  float4 p  = ((const float4*)prev)[idx];
  float4 nz = ((const float4*)noise)[idx];
  float4 ap = make_float4(A_C*p.x, A_C*p.y, A_C*p.z, A_C*p.w);
  float4 x  = make_float4(ap.x+nz.x, ap.y+nz.y, ap.z+nz.z, ap.w+nz.w);
  ((float4*)x0)[idx]  = x;
  ((float4*)apb)[idx] = ap;
  ((int4*)hists)[idx] = make_int4(0, 0, 0, 0);  // 16384*4 = 65536 ints
  if (idx < 64) ctrs[idx] = 0;
}

// ---------- histogram + fused scan (exact radix-select, top 24 bits)
// Unordered pairs (i, (i+k) mod N), k = 1..1024 (k==1024 only for i<1024),
// weight 2; +N virtual diagonal zeros added at scan time.
// PHASE 0: bits[31:20] -> 4096 bins.  PHASE 1: bits[19:8], filtered on sel0.
// Last finishing block of each batch performs the rank-scan in-kernel and
// re-zeroes that batch's histogram for the next iteration.
template <int PHASE>
__global__ __launch_bounds__(256) void k_hist(const float* __restrict__ x,
                                              int* __restrict__ state,
                                              int* __restrict__ hist,
                                              int* __restrict__ ctr,
                                              float* __restrict__ hpar) {
  int b    = blockIdx.x >> 7;       // 128 blocks per batch
  int sub  = blockIdx.x & 127;
  int itile = sub >> 4;             // 8 i-tiles of 256
  int ktile = sub & 15;             // 16 k-tiles of 64
  __shared__ int sh[4096];          // 16 KB
  __shared__ int lastflag;
  for (int t = threadIdx.x; t < 4096; t += 256) sh[t] = 0;
  int sel0 = (PHASE == 1) ? state[b*4 + 0] : 0;
  __syncthreads();

  int i = itile*256 + threadIdx.x;
  const float4* xb = (const float4*)x + b*NPART;
  float4 xi = xb[i];
  int k0 = ktile*64 + 1;
#pragma unroll 8
  for (int kk = 0; kk < 64; ++kk) {
    int k = k0 + kk;
    int j = (i + k) & (NPART - 1);
    float4 xj = xb[j];
    float dx = xi.x - xj.x, dy = xi.y - xj.y;
    float dz = xi.z - xj.z, dw = xi.w - xj.w;
    float sq = dx*dx + dy*dy + dz*dz + dw*dw;   // >= 0 by construction
    unsigned bits = __float_as_uint(sq);
    bool ok = (k != 1024) || (i < 1024);
    if (PHASE == 0) {
      if (ok) atomicAdd(&sh[bits >> 20], 2);
    } else {
      if (ok && (int)(bits >> 20) == sel0) atomicAdd(&sh[(bits >> 8) & 4095], 2);
    }
  }
  __syncthreads();
  int* hb = hist + b*4096;
  for (int t = threadIdx.x; t < 4096; t += 256) {
    int c = sh[t];
    if (c) atomicAdd(&hb[t], c);
  }
  // ---- last-block-per-batch does the scan
  __threadfence();
  if (threadIdx.x == 0) {
    int old = atomicAdd(&ctr[b], 1);
    lastflag = (old == 127);
  }
  __syncthreads();
  if (!lastflag) return;
  __threadfence();

  __shared__ int part[256];
  int s = 0;
  for (int c = 0; c < 16; ++c)
    s += __hip_atomic_load(&hb[threadIdx.x*16 + c], __ATOMIC_RELAXED,
                           __HIP_MEMORY_SCOPE_AGENT);
  if (threadIdx.x == 0 && (PHASE == 0 || sel0 == 0)) s += NPART;  // diagonal
  part[threadIdx.x] = s;
  __syncthreads();
  if (threadIdx.x == 0) {
    int r = (PHASE == 0) ? KRANK : state[b*4 + 2];
    int cum = 0, ch = 0;
    for (; ch < 256; ++ch) { if (cum + part[ch] > r) break; cum += part[ch]; }
    int bin = ch * 16;
    for (;; ++bin) {
      int c = __hip_atomic_load(&hb[bin], __ATOMIC_RELAXED,
                                __HIP_MEMORY_SCOPE_AGENT)
              + ((bin == 0 && (PHASE == 0 || sel0 == 0)) ? NPART : 0);
      if (cum + c > r) break;
      cum += c;
    }
    if (PHASE == 0) {
      state[b*4 + 0] = bin;
      state[b*4 + 2] = r - cum;
    } else {
      // top 24 bits exact; low 8 bits -> midpoint (rel err <= 2^-16)
      unsigned mb = (((unsigned)sel0) << 20) | (((unsigned)bin) << 8) | 128u;
      float med = sqrtf(__uint_as_float(mb));
      float h = med * med / LOGN_F;
      hpar[b*4 + 1] = -1.0f / h;
      hpar[b*4 + 2] = 2.0f / h;
    }
  }
  __syncthreads();   // scan reads of hb must complete before re-zero
  for (int t = threadIdx.x; t < 4096; t += 256) hb[t] = 0;
}

// ---------- posterior gradient, single pass, no LDS.
// softmax logit over j: -0.5|x_i - ap_j|^2  (<= 0; max-shift analytic).
// g_i = sum_j w_ij * ap_j + obs - 2 x_i
// 16 threads per particle; 1024 blocks.
__global__ __launch_bounds__(256) void k_grad(const float* __restrict__ x,
                                              const float* __restrict__ apb,
                                              const float* __restrict__ obs,
                                              float* __restrict__ g) {
  int b   = blockIdx.x >> 7;          // 128 blocks/batch, 16 particles/block
  int ip  = threadIdx.x >> 4;
  int sub = threadIdx.x & 15;
  int i = (blockIdx.x & 127)*16 + ip;
  const float4* ab = (const float4*)apb + b*NPART;
  float4 xi = ((const float4*)x)[b*NPART + i];

  float sum = 0.f;
  float4 acc = make_float4(0.f, 0.f, 0.f, 0.f);
#pragma unroll 8
  for (int c = 0; c < 128; ++c) {
    int j = sub + 16*c;
    float4 ap = ab[j];
    float dx = xi.x - ap.x, dy = xi.y - ap.y;
    float dz = xi.z - ap.z, dw = xi.w - ap.w;
    float e = __expf(-0.5f*(dx*dx + dy*dy + dz*dz + dw*dw));
    sum += e;
    acc.x += e*ap.x; acc.y += e*ap.y; acc.z += e*ap.z; acc.w += e*ap.w;
  }
#pragma unroll
  for (int d = 1; d < 16; d <<= 1) {
    sum   += __shfl_xor(sum, d);
    acc.x += __shfl_xor(acc.x, d);
    acc.y += __shfl_xor(acc.y, d);
    acc.z += __shfl_xor(acc.z, d);
    acc.w += __shfl_xor(acc.w, d);
  }
  if (sub == 0) {
    float inv = 1.0f / sum;
    float4 ob = ((const float4*)obs)[b];
    float4 gg;
    gg.x = acc.x*inv + ob.x - 2.0f*xi.x;
    gg.y = acc.y*inv + ob.y - 2.0f*xi.y;
    gg.z = acc.z*inv + ob.z - 2.0f*xi.z;
    gg.w = acc.w*inv + ob.w - 2.0f*xi.w;
    ((float4*)g)[b*NPART + i] = gg;
  }
}

// ---------- stein pass + RMSprop update, no LDS.
// stein_i = ( sum_j e_ij g_j + (2/h) sum_j e_ij (x_i - x_j) ) / N
// MODE 0: first iter (stepb write, no read).  MODE 1: middle.
// MODE 2: last iter (writes (B,N,5) output directly, no stepb/x write).
template <int MODE>
__global__ __launch_bounds__(256) void k_stein(const float* __restrict__ x,
                                               const float* __restrict__ g,
                                               const float* __restrict__ hpar,
                                               float* __restrict__ stepb,
                                               float* __restrict__ xout,
                                               float* __restrict__ outp) {
  int b   = blockIdx.x >> 7;
  int ip  = threadIdx.x >> 4;
  int sub = threadIdx.x & 15;
  int i = (blockIdx.x & 127)*16 + ip;
  const float4* xb = (const float4*)x + b*NPART;
  const float4* gb = (const float4*)g + b*NPART;
  float neginvh = hpar[b*4 + 1];
  float two_h   = hpar[b*4 + 2];
  float4 xi = xb[i];

  float4 Sd = make_float4(0.f,0.f,0.f,0.f);
  float4 Sg = make_float4(0.f,0.f,0.f,0.f);
#pragma unroll 8
  for (int c = 0; c < 128; ++c) {
    int j = sub + 16*c;
    float4 xj = xb[j];
    float4 gj = gb[j];
    float dx = xi.x - xj.x, dy = xi.y - xj.y;
    float dz = xi.z - xj.z, dw = xi.w - xj.w;
    float sq = dx*dx + dy*dy + dz*dz + dw*dw;
    float e = __expf(sq * neginvh);
    Sd.x += e*dx; Sd.y += e*dy; Sd.z += e*dz; Sd.w += e*dw;
    Sg.x += e*gj.x; Sg.y += e*gj.y; Sg.z += e*gj.z; Sg.w += e*gj.w;
  }
#pragma unroll
  for (int d = 1; d < 16; d <<= 1) {
    Sd.x += __shfl_xor(Sd.x, d); Sd.y += __shfl_xor(Sd.y, d);
    Sd.z += __shfl_xor(Sd.z, d); Sd.w += __shfl_xor(Sd.w, d);
    Sg.x += __shfl_xor(Sg.x, d); Sg.y += __shfl_xor(Sg.y, d);
    Sg.z += __shfl_xor(Sg.z, d); Sg.w += __shfl_xor(Sg.w, d);
  }
  if (sub == 0) {
    const float invN = 1.0f / 2048.0f;
    float4 sv;
    sv.x = (Sg.x + two_h*Sd.x) * invN;
    sv.y = (Sg.y + two_h*Sd.y) * invN;
    sv.z = (Sg.z + two_h*Sd.z) * invN;
    sv.w = (Sg.w + two_h*Sd.w) * invN;
    float4 st;
    if (MODE == 0) {
      st = make_float4(0.1f*sv.x*sv.x, 0.1f*sv.y*sv.y,
                       0.1f*sv.z*sv.z, 0.1f*sv.w*sv.w);
    } else {
      st = ((float4*)stepb)[b*NPART + i];
      st.x = 0.9f*st.x + 0.1f*sv.x*sv.x;
      st.y = 0.9f*st.y + 0.1f*sv.y*sv.y;
      st.z = 0.9f*st.z + 0.1f*sv.z*sv.z;
      st.w = 0.9f*st.w + 0.1f*sv.w*sv.w;
    }
    float4 xn;
    xn.x = xi.x + 0.1f*sv.x / (sqrtf(st.x) + 1e-8f);
    xn.y = xi.y + 0.1f*sv.y / (sqrtf(st.y) + 1e-8f);
    xn.z = xi.z + 0.1f*sv.z / (sqrtf(st.z) + 1e-8f);
    xn.w = xi.w + 0.1f*sv.w / (sqrtf(st.w) + 1e-8f);
    if (MODE != 2) {
      ((float4*)stepb)[b*NPART + i] = st;
      ((float4*)xout)[b*NPART + i] = xn;
    } else {
      float* o = outp + (size_t)(b*NPART + i) * 5;
      o[0] = xn.x; o[1] = xn.y; o[2] = xn.z; o[3] = xn.w;
      o[4] = -LOGN_F;
    }
  }
}

extern "C" void kernel_launch(void* const* d_in, const int* in_sizes, int n_in,
                              void* d_out, int out_size, void* d_ws, size_t ws_size,
                              hipStream_t stream) {
  const float* prev  = (const float*)d_in[0];   // (8,2048,4)
  const float* obs   = (const float*)d_in[1];   // (8,4)
  const float* noise = (const float*)d_in[2];   // (8,2048,4)
  float* out = (float*)d_out;                   // (8,2048,5)

  float* ws = (float*)d_ws;
  float* xA    = ws;
  float* xB    = xA + 65536;
  float* gbuf  = xB + 65536;
  float* stepb = gbuf + 65536;
  float* apb   = stepb + 65536;
  float* hpar  = apb + 65536;               // 32 floats
  int*   state = (int*)(hpar + 32);         // 32 ints
  int*   hist0 = state + 32;                // 8*4096 ints
  int*   hist1 = hist0 + 8*4096;            // 8*4096 ints
  int*   ctrs  = hist1 + 8*4096;            // 64 ints (6 used groups of 8)

  k_init<<<64, 256, 0, stream>>>(prev, noise, xA, apb, hist0, ctrs);

  float* xc = xA;
  float* xn = xB;
  for (int it = 0; it < 3; ++it) {
    k_grad<<<1024, 256, 0, stream>>>(xc, apb, obs, gbuf);
    k_hist<0><<<1024, 256, 0, stream>>>(xc, state, hist0, ctrs + it*16,     hpar);
    k_hist<1><<<1024, 256, 0, stream>>>(xc, state, hist1, ctrs + it*16 + 8, hpar);
    if (it == 0) {
      k_stein<0><<<1024, 256, 0, stream>>>(xc, gbuf, hpar, stepb, xn, nullptr);
    } else if (it == 1) {
      k_stein<1><<<1024, 256, 0, stream>>>(xc, gbuf, hpar, stepb, xn, nullptr);
    } else {
      k_stein<2><<<1024, 256, 0, stream>>>(xc, gbuf, hpar, stepb, nullptr, out);
    }
    float* t = xc; xc = xn; xn = t;
  }
}

// Round 4
// 491.847 us; speedup vs baseline: 1.4988x; 1.4988x over previous
//
#include <hip/hip_runtime.h>
#include <math.h>

// SVPF step: B=8, N=2048, D=4, fp32.  3 SVGD iterations.
// log_weight output channel is exactly -log(2048) (log_post cancels).
//
// R4 changes vs R3 (diagnosis: R3 k_hist had VGPR=12 / VALUBusy=6% -> compiler
// serialized the per-pair global loads; 64 exposed ~150cy latencies/thread):
//  - k_hist reads x from LDS again, but stages only the 9KB window the block
//    needs (sxi[256] + sxw[320]); phase-0 hist is 2048 bins (sign bit always
//    0) -> 17KB/26KB LDS -> 6-9 blocks/CU.  k=1024 edge case is a uniform
//    loop bound (no per-lane branch in the body).
//  - threadfence: one per block (thread 0), not 256; reader-side fence only
//    in the scanning block.  __syncthreads() drains the flush atomics.
//  - k_grad / k_stein keep R3's no-LDS global reads (those pipelined fine)
//    plus manual 2-way ILP: j and j+1024 chains with separate accumulators.
//
// ws layout (floats):
//   xA[65536] xB[65536] g[65536] step[65536] ap[65536]
//   hpar[32] state[32 ints]
//   hist0[8*2048 ints] hist1[8*4096 ints] ctr[64 ints]  (zeroed by k_init)

#define NPART 2048
#define KRANK 2097151               // (2048*2048-1)/2, lower-median rank
#define LOGN_F 7.6246189861593985f  // log(2048)
#define A_C 0.9f

__device__ __forceinline__ int aload(const int* p) {
  return __hip_atomic_load(p, __ATOMIC_RELAXED, __HIP_MEMORY_SCOPE_AGENT);
}

// ---------- init: x0 = A*prev + noise; ap = A*prev; zero hists + counters
__global__ __launch_bounds__(256) void k_init(const float* __restrict__ prev,
                                              const float* __restrict__ noise,
                                              float* __restrict__ x0,
                                              float* __restrict__ apb,
                                              int* __restrict__ hists) {
  int idx = blockIdx.x * 256 + threadIdx.x;   // 0..16383 (B*N)
  float4 p  = ((const float4*)prev)[idx];
  float4 nz = ((const float4*)noise)[idx];
  float4 ap = make_float4(A_C*p.x, A_C*p.y, A_C*p.z, A_C*p.w);
  float4 x  = make_float4(ap.x+nz.x, ap.y+nz.y, ap.z+nz.z, ap.w+nz.w);
  ((float4*)x0)[idx]  = x;
  ((float4*)apb)[idx] = ap;
  // zero hist0(16384) + hist1(32768) + ctr(64) <= 65536 ints, 4 per thread
  ((int4*)hists)[idx] = make_int4(0, 0, 0, 0);
}

// ---------- histogram + fused scan (exact radix-select, top 24 bits)
// Unordered pairs (i, (i+k) mod N), k = 1..1024 (k==1024 only for i<1024),
// weight 2; +N virtual diagonal zeros at scan time.
// PHASE 0: bits[31:20] (sign=0 -> 2048 bins).  PHASE 1: bits[19:8] (4096),
// filtered on sel0.  Last finishing block per batch scans + re-zeroes.
template <int PHASE>
__global__ __launch_bounds__(256) void k_hist(const float* __restrict__ x,
                                              int* __restrict__ state,
                                              int* __restrict__ hist,
                                              int* __restrict__ ctr,
                                              float* __restrict__ hpar) {
  constexpr int NBIN = (PHASE == 0) ? 2048 : 4096;
  constexpr int CH   = NBIN / 256;
  int b     = blockIdx.x >> 7;      // 128 blocks per batch
  int sub   = blockIdx.x & 127;
  int itile = sub >> 4;             // 8 i-tiles of 256
  int ktile = sub & 15;             // 16 k-tiles of 64
  __shared__ float4 sxi[256];       // 4 KB
  __shared__ float4 sxw[320];       // 5 KB
  __shared__ int    sh[NBIN];       // 8 / 16 KB
  __shared__ int    part[256];
  __shared__ int    lastflag;

  const float4* xb = (const float4*)x + b*NPART;
  int ibase = itile*256;
  int k0 = ktile*64 + 1;
  sxi[threadIdx.x] = xb[ibase + threadIdx.x];
  for (int t = threadIdx.x; t < 320; t += 256)
    sxw[t] = xb[(ibase + k0 + t) & (NPART - 1)];
  for (int t = threadIdx.x; t < NBIN; t += 256) sh[t] = 0;
  int sel0 = (PHASE == 1) ? state[b*4 + 0] : 0;
  __syncthreads();

  float4 xi = sxi[threadIdx.x];
  // k = k0+kk; k==1024 happens only at (ktile==15, kk==63) and should count
  // only for i<1024 <=> itile<4  -> uniform loop bound, no per-lane branch.
  int kmax = (ktile == 15 && itile >= 4) ? 63 : 64;
  for (int kk = 0; kk < kmax; ++kk) {
    float4 xj = sxw[threadIdx.x + kk];
    float dx = xi.x - xj.x, dy = xi.y - xj.y;
    float dz = xi.z - xj.z, dw = xi.w - xj.w;
    float sq = dx*dx + dy*dy + dz*dz + dw*dw;   // >= 0 by construction
    unsigned bits = __float_as_uint(sq);
    if (PHASE == 0) {
      atomicAdd(&sh[bits >> 20], 2);
    } else {
      if ((int)(bits >> 20) == sel0) atomicAdd(&sh[(bits >> 8) & 4095], 2);
    }
  }
  __syncthreads();
  int* hb = hist + b*NBIN;
  for (int t = threadIdx.x; t < NBIN; t += 256) {
    int c = sh[t];
    if (c) atomicAdd(&hb[t], c);
  }
  __syncthreads();                  // drains every thread's flush atomics
  if (threadIdx.x == 0) {
    __threadfence();                // order flushes before the counter add
    lastflag = (atomicAdd(&ctr[b], 1) == 127);
  }
  __syncthreads();
  if (!lastflag) return;

  // ---- last block of this batch: rank-scan, publish, re-zero
  __threadfence();
  int s = 0;
  for (int c = 0; c < CH; ++c) s += aload(&hb[threadIdx.x*CH + c]);
  if (threadIdx.x == 0 && (PHASE == 0 || sel0 == 0)) s += NPART;  // diagonal
  part[threadIdx.x] = s;
  __syncthreads();
  if (threadIdx.x == 0) {
    int r = (PHASE == 0) ? KRANK : state[b*4 + 2];
    int cum = 0, ch = 0;
    for (; ch < 256; ++ch) { if (cum + part[ch] > r) break; cum += part[ch]; }
    int bin = ch * CH;
    for (;; ++bin) {
      int c = aload(&hb[bin]) +
              ((bin == 0 && (PHASE == 0 || sel0 == 0)) ? NPART : 0);
      if (cum + c > r) break;
      cum += c;
    }
    if (PHASE == 0) {
      state[b*4 + 0] = bin;
      state[b*4 + 2] = r - cum;
    } else {
      // top 24 bits exact; low 8 bits -> midpoint (rel err <= 2^-16)
      unsigned mb = (((unsigned)sel0) << 20) | (((unsigned)bin) << 8) | 128u;
      float med = sqrtf(__uint_as_float(mb));
      float h = med * med / LOGN_F;
      hpar[b*4 + 1] = -1.0f / h;
      hpar[b*4 + 2] = 2.0f / h;
    }
  }
  __syncthreads();   // scan reads of hb complete before re-zero
  for (int t = threadIdx.x; t < NBIN; t += 256) hb[t] = 0;
}

// ---------- posterior gradient, single pass, no LDS, 2-way ILP.
// softmax logit over j: -0.5|x_i - ap_j|^2  (<= 0; max-shift analytic).
// g_i = sum_j w_ij * ap_j + obs - 2 x_i.  16 threads/particle, 1024 blocks.
__global__ __launch_bounds__(256) void k_grad(const float* __restrict__ x,
                                              const float* __restrict__ apb,
                                              const float* __restrict__ obs,
                                              float* __restrict__ g) {
  int b   = blockIdx.x >> 7;          // 128 blocks/batch, 16 particles/block
  int ip  = threadIdx.x >> 4;
  int sub = threadIdx.x & 15;
  int i = (blockIdx.x & 127)*16 + ip;
  const float4* ab = (const float4*)apb + b*NPART;
  float4 xi = ((const float4*)x)[b*NPART + i];

  float sum1 = 0.f, sum2 = 0.f;
  float4 acc1 = make_float4(0.f,0.f,0.f,0.f);
  float4 acc2 = make_float4(0.f,0.f,0.f,0.f);
#pragma unroll 4
  for (int c = 0; c < 64; ++c) {
    int j = sub + 16*c;
    float4 a1 = ab[j];
    float4 a2 = ab[j + 1024];
    float dx1 = xi.x-a1.x, dy1 = xi.y-a1.y, dz1 = xi.z-a1.z, dw1 = xi.w-a1.w;
    float dx2 = xi.x-a2.x, dy2 = xi.y-a2.y, dz2 = xi.z-a2.z, dw2 = xi.w-a2.w;
    float e1 = __expf(-0.5f*(dx1*dx1 + dy1*dy1 + dz1*dz1 + dw1*dw1));
    float e2 = __expf(-0.5f*(dx2*dx2 + dy2*dy2 + dz2*dz2 + dw2*dw2));
    sum1 += e1; sum2 += e2;
    acc1.x += e1*a1.x; acc1.y += e1*a1.y; acc1.z += e1*a1.z; acc1.w += e1*a1.w;
    acc2.x += e2*a2.x; acc2.y += e2*a2.y; acc2.z += e2*a2.z; acc2.w += e2*a2.w;
  }
  float sum = sum1 + sum2;
  float4 acc = make_float4(acc1.x+acc2.x, acc1.y+acc2.y,
                           acc1.z+acc2.z, acc1.w+acc2.w);
#pragma unroll
  for (int d = 1; d < 16; d <<= 1) {
    sum   += __shfl_xor(sum, d);
    acc.x += __shfl_xor(acc.x, d);
    acc.y += __shfl_xor(acc.y, d);
    acc.z += __shfl_xor(acc.z, d);
    acc.w += __shfl_xor(acc.w, d);
  }
  if (sub == 0) {
    float inv = 1.0f / sum;
    float4 ob = ((const float4*)obs)[b];
    float4 gg;
    gg.x = acc.x*inv + ob.x - 2.0f*xi.x;
    gg.y = acc.y*inv + ob.y - 2.0f*xi.y;
    gg.z = acc.z*inv + ob.z - 2.0f*xi.z;
    gg.w = acc.w*inv + ob.w - 2.0f*xi.w;
    ((float4*)g)[b*NPART + i] = gg;
  }
}

// ---------- stein pass + RMSprop update, no LDS, 2-way ILP.
// stein_i = ( sum_j e_ij g_j + (2/h) sum_j e_ij (x_i - x_j) ) / N
// MODE 0: first iter.  MODE 1: middle.  MODE 2: last (writes (B,N,5) out).
template <int MODE>
__global__ __launch_bounds__(256) void k_stein(const float* __restrict__ x,
                                               const float* __restrict__ g,
                                               const float* __restrict__ hpar,
                                               float* __restrict__ stepb,
                                               float* __restrict__ xout,
                                               float* __restrict__ outp) {
  int b   = blockIdx.x >> 7;
  int ip  = threadIdx.x >> 4;
  int sub = threadIdx.x & 15;
  int i = (blockIdx.x & 127)*16 + ip;
  const float4* xb = (const float4*)x + b*NPART;
  const float4* gb = (const float4*)g + b*NPART;
  float neginvh = hpar[b*4 + 1];
  float two_h   = hpar[b*4 + 2];
  float4 xi = xb[i];

  float4 Sd1 = make_float4(0.f,0.f,0.f,0.f), Sd2 = Sd1;
  float4 Sg1 = Sd1, Sg2 = Sd1;
#pragma unroll 4
  for (int c = 0; c < 64; ++c) {
    int j = sub + 16*c;
    float4 xj1 = xb[j];
    float4 xj2 = xb[j + 1024];
    float4 gj1 = gb[j];
    float4 gj2 = gb[j + 1024];
    float dx1 = xi.x-xj1.x, dy1 = xi.y-xj1.y, dz1 = xi.z-xj1.z, dw1 = xi.w-xj1.w;
    float dx2 = xi.x-xj2.x, dy2 = xi.y-xj2.y, dz2 = xi.z-xj2.z, dw2 = xi.w-xj2.w;
    float e1 = __expf((dx1*dx1 + dy1*dy1 + dz1*dz1 + dw1*dw1) * neginvh);
    float e2 = __expf((dx2*dx2 + dy2*dy2 + dz2*dz2 + dw2*dw2) * neginvh);
    Sd1.x += e1*dx1; Sd1.y += e1*dy1; Sd1.z += e1*dz1; Sd1.w += e1*dw1;
    Sd2.x += e2*dx2; Sd2.y += e2*dy2; Sd2.z += e2*dz2; Sd2.w += e2*dw2;
    Sg1.x += e1*gj1.x; Sg1.y += e1*gj1.y; Sg1.z += e1*gj1.z; Sg1.w += e1*gj1.w;
    Sg2.x += e2*gj2.x; Sg2.y += e2*gj2.y; Sg2.z += e2*gj2.z; Sg2.w += e2*gj2.w;
  }
  float4 Sd = make_float4(Sd1.x+Sd2.x, Sd1.y+Sd2.y, Sd1.z+Sd2.z, Sd1.w+Sd2.w);
  float4 Sg = make_float4(Sg1.x+Sg2.x, Sg1.y+Sg2.y, Sg1.z+Sg2.z, Sg1.w+Sg2.w);
#pragma unroll
  for (int d = 1; d < 16; d <<= 1) {
    Sd.x += __shfl_xor(Sd.x, d); Sd.y += __shfl_xor(Sd.y, d);
    Sd.z += __shfl_xor(Sd.z, d); Sd.w += __shfl_xor(Sd.w, d);
    Sg.x += __shfl_xor(Sg.x, d); Sg.y += __shfl_xor(Sg.y, d);
    Sg.z += __shfl_xor(Sg.z, d); Sg.w += __shfl_xor(Sg.w, d);
  }
  if (sub == 0) {
    const float invN = 1.0f / 2048.0f;
    float4 sv;
    sv.x = (Sg.x + two_h*Sd.x) * invN;
    sv.y = (Sg.y + two_h*Sd.y) * invN;
    sv.z = (Sg.z + two_h*Sd.z) * invN;
    sv.w = (Sg.w + two_h*Sd.w) * invN;
    float4 st;
    if (MODE == 0) {
      st = make_float4(0.1f*sv.x*sv.x, 0.1f*sv.y*sv.y,
                       0.1f*sv.z*sv.z, 0.1f*sv.w*sv.w);
    } else {
      st = ((float4*)stepb)[b*NPART + i];
      st.x = 0.9f*st.x + 0.1f*sv.x*sv.x;
      st.y = 0.9f*st.y + 0.1f*sv.y*sv.y;
      st.z = 0.9f*st.z + 0.1f*sv.z*sv.z;
      st.w = 0.9f*st.w + 0.1f*sv.w*sv.w;
    }
    float4 xn;
    xn.x = xi.x + 0.1f*sv.x / (sqrtf(st.x) + 1e-8f);
    xn.y = xi.y + 0.1f*sv.y / (sqrtf(st.y) + 1e-8f);
    xn.z = xi.z + 0.1f*sv.z / (sqrtf(st.z) + 1e-8f);
    xn.w = xi.w + 0.1f*sv.w / (sqrtf(st.w) + 1e-8f);
    if (MODE != 2) {
      ((float4*)stepb)[b*NPART + i] = st;
      ((float4*)xout)[b*NPART + i] = xn;
    } else {
      float* o = outp + (size_t)(b*NPART + i) * 5;
      o[0] = xn.x; o[1] = xn.y; o[2] = xn.z; o[3] = xn.w;
      o[4] = -LOGN_F;
    }
  }
}

extern "C" void kernel_launch(void* const* d_in, const int* in_sizes, int n_in,
                              void* d_out, int out_size, void* d_ws, size_t ws_size,
                              hipStream_t stream) {
  const float* prev  = (const float*)d_in[0];   // (8,2048,4)
  const float* obs   = (const float*)d_in[1];   // (8,4)
  const float* noise = (const float*)d_in[2];   // (8,2048,4)
  float* out = (float*)d_out;                   // (8,2048,5)

  float* ws = (float*)d_ws;
  float* xA    = ws;
  float* xB    = xA + 65536;
  float* gbuf  = xB + 65536;
  float* stepb = gbuf + 65536;
  float* apb   = stepb + 65536;
  float* hpar  = apb + 65536;               // 32 floats
  int*   state = (int*)(hpar + 32);         // 32 ints
  int*   hist0 = state + 32;                // 8*2048 ints
  int*   hist1 = hist0 + 8*2048;            // 8*4096 ints
  int*   ctrs  = hist1 + 8*4096;            // 64 ints (48 used)

  k_init<<<64, 256, 0, stream>>>(prev, noise, xA, apb, hist0);

  float* xc = xA;
  float* xn = xB;
  for (int it = 0; it < 3; ++it) {
    k_grad<<<1024, 256, 0, stream>>>(xc, apb, obs, gbuf);
    k_hist<0><<<1024, 256, 0, stream>>>(xc, state, hist0, ctrs + it*16,     hpar);
    k_hist<1><<<1024, 256, 0, stream>>>(xc, state, hist1, ctrs + it*16 + 8, hpar);
    if (it == 0) {
      k_stein<0><<<1024, 256, 0, stream>>>(xc, gbuf, hpar, stepb, xn, nullptr);
    } else if (it == 1) {
      k_stein<1><<<1024, 256, 0, stream>>>(xc, gbuf, hpar, stepb, xn, nullptr);
    } else {
      k_stein<2><<<1024, 256, 0, stream>>>(xc, gbuf, hpar, stepb, nullptr, out);
    }
    float* t = xc; xc = xn; xn = t;
  }
}

// Round 5
// 382.058 us; speedup vs baseline: 1.9295x; 1.2874x over previous
//
#include <hip/hip_runtime.h>
#include <math.h>

// SVPF step: B=8, N=2048, D=4, fp32.  3 SVGD iterations.
// log_weight output channel is exactly -log(2048) (log_post cancels).
//
// R5 changes vs R4 (diagnosis: __threadfence() per block = XCD-L2
// writeback/invalidate; 1024 of them = ~50 us of the 57 us k_hist time;
// VALUBusy 9% matched "loop itself is only ~5 us" exactly):
//  - NO fences, NO arrival counters: k_hist flushes LDS hist via global
//    atomics and exits; separate k_scan0/k_scan1 kernels (8 blocks) do the
//    rank walk (kernel boundary provides ordering, as in R2).
//  - hist inner loop: uniform 64 iterations, #pragma unroll 4; the k==1024
//    duplicate-pair edge uses weight 1 instead of 2 (pair visited twice ->
//    still exact), so no runtime-variable loop bound.
//  - k_grad / k_stein / k_init unchanged from R4.
//
// ws layout (floats):
//   xA[65536] xB[65536] g[65536] step[65536] ap[65536]
//   hpar[32] state[32 ints]
//   hist0[8*2048 ints] hist1[8*4096 ints] (+pad; zeroed by k_init)

#define NPART 2048
#define KRANK 2097151               // (2048*2048-1)/2, lower-median rank
#define LOGN_F 7.6246189861593985f  // log(2048)
#define A_C 0.9f

// ---------- init: x0 = A*prev + noise; ap = A*prev; zero hists
__global__ __launch_bounds__(256) void k_init(const float* __restrict__ prev,
                                              const float* __restrict__ noise,
                                              float* __restrict__ x0,
                                              float* __restrict__ apb,
                                              int* __restrict__ hists) {
  int idx = blockIdx.x * 256 + threadIdx.x;   // 0..16383 (B*N)
  float4 p  = ((const float4*)prev)[idx];
  float4 nz = ((const float4*)noise)[idx];
  float4 ap = make_float4(A_C*p.x, A_C*p.y, A_C*p.z, A_C*p.w);
  float4 x  = make_float4(ap.x+nz.x, ap.y+nz.y, ap.z+nz.z, ap.w+nz.w);
  ((float4*)x0)[idx]  = x;
  ((float4*)apb)[idx] = ap;
  // zero hist0(16384 ints) + hist1(32768 ints) + pad = 65536 ints
  ((int4*)hists)[idx] = make_int4(0, 0, 0, 0);
}

// ---------- histogram passes (exact radix-select, top 24 bits)
// Unordered pairs (i, (i+k) mod N), k = 1..1024.  k<=1023: weight 2 (pair
// seen once, stands for both ordered pairs).  k==1024: weight 1 (each such
// pair is visited twice: at i and i+1024).  +N diagonal zeros at scan time.
// PHASE 0: bits[31:20] (sign=0 -> 2048 bins).  PHASE 1: bits[19:8] (4096),
// filtered on sel0.
template <int PHASE>
__global__ __launch_bounds__(256) void k_hist(const float* __restrict__ x,
                                              const int* __restrict__ state,
                                              int* __restrict__ hist) {
  constexpr int NBIN = (PHASE == 0) ? 2048 : 4096;
  int b     = blockIdx.x >> 7;      // 128 blocks per batch
  int sub   = blockIdx.x & 127;
  int itile = sub >> 4;             // 8 i-tiles of 256
  int ktile = sub & 15;             // 16 k-tiles of 64
  __shared__ float4 sxi[256];       // 4 KB
  __shared__ float4 sxw[320];       // 5 KB
  __shared__ int    sh[NBIN];       // 8 / 16 KB

  const float4* xb = (const float4*)x + b*NPART;
  int ibase = itile*256;
  int k0 = ktile*64 + 1;
  sxi[threadIdx.x] = xb[ibase + threadIdx.x];
  for (int t = threadIdx.x; t < 320; t += 256)
    sxw[t] = xb[(ibase + k0 + t) & (NPART - 1)];
  for (int t = threadIdx.x; t < NBIN; t += 256) sh[t] = 0;
  int sel0 = (PHASE == 1) ? state[b*4 + 0] : 0;
  __syncthreads();

  float4 xi = sxi[threadIdx.x];
#pragma unroll 4
  for (int kk = 0; kk < 64; ++kk) {
    int w = (ktile == 15 && kk == 63) ? 1 : 2;   // wave-uniform
    float4 xj = sxw[threadIdx.x + kk];
    float dx = xi.x - xj.x, dy = xi.y - xj.y;
    float dz = xi.z - xj.z, dw = xi.w - xj.w;
    float sq = dx*dx + dy*dy + dz*dz + dw*dw;   // >= 0 by construction
    unsigned bits = __float_as_uint(sq);
    if (PHASE == 0) {
      atomicAdd(&sh[bits >> 20], w);
    } else {
      if ((int)(bits >> 20) == sel0) atomicAdd(&sh[(bits >> 8) & 4095], w);
    }
  }
  __syncthreads();
  int* hb = hist + b*NBIN;
  for (int t = threadIdx.x; t < NBIN; t += 256) {
    int c = sh[t];
    if (c) atomicAdd(&hb[t], c);
  }
}

// ---------- scan phase 0: find high-12-bit bin containing rank KRANK
__global__ __launch_bounds__(256) void k_scan0(const int* __restrict__ hist0,
                                               int* __restrict__ state) {
  int b = blockIdx.x;
  __shared__ int part[256];
  int s = 0;
  for (int c = 0; c < 8; ++c) s += hist0[b*2048 + threadIdx.x*8 + c];
  if (threadIdx.x == 0) s += NPART;   // diagonal zeros -> bin 0
  part[threadIdx.x] = s;
  __syncthreads();
  if (threadIdx.x == 0) {
    int r = KRANK, cum = 0, ch = 0;
    for (; ch < 256; ++ch) { if (cum + part[ch] > r) break; cum += part[ch]; }
    int bin = ch * 8;
    for (;; ++bin) {
      int c = hist0[b*2048 + bin] + ((bin == 0) ? NPART : 0);
      if (cum + c > r) break;
      cum += c;
    }
    state[b*4 + 0] = bin;
    state[b*4 + 2] = r - cum;
  }
}

// ---------- scan phase 1: finalize h; re-zero both hists for next iteration
__global__ __launch_bounds__(256) void k_scan1(int* __restrict__ hist0,
                                               int* __restrict__ hist1,
                                               const int* __restrict__ state,
                                               float* __restrict__ hpar) {
  int b = blockIdx.x;
  __shared__ int part[256];
  int sel0 = state[b*4 + 0];
  int s = 0;
  for (int c = 0; c < 16; ++c) s += hist1[b*4096 + threadIdx.x*16 + c];
  if (threadIdx.x == 0 && sel0 == 0) s += NPART;  // zeros in bin 0 iff sel0==0
  part[threadIdx.x] = s;
  __syncthreads();
  if (threadIdx.x == 0) {
    int r = state[b*4 + 2], cum = 0, ch = 0;
    for (; ch < 256; ++ch) { if (cum + part[ch] > r) break; cum += part[ch]; }
    int bin = ch * 16;
    for (;; ++bin) {
      int c = hist1[b*4096 + bin] + ((sel0 == 0 && bin == 0) ? NPART : 0);
      if (cum + c > r) break;
      cum += c;
    }
    // top 24 bits exact; low 8 bits -> midpoint (rel err <= 2^-16)
    unsigned mb = (((unsigned)sel0) << 20) | (((unsigned)bin) << 8) | 128u;
    float med = sqrtf(__uint_as_float(mb));
    float h = med * med / LOGN_F;
    hpar[b*4 + 1] = -1.0f / h;
    hpar[b*4 + 2] = 2.0f / h;
  }
  __syncthreads();
  for (int t = threadIdx.x; t < 2048; t += 256) hist0[b*2048 + t] = 0;
  for (int t = threadIdx.x; t < 4096; t += 256) hist1[b*4096 + t] = 0;
}

// ---------- posterior gradient, single pass, no LDS, 2-way ILP.
// softmax logit over j: -0.5|x_i - ap_j|^2  (<= 0; max-shift analytic).
// g_i = sum_j w_ij * ap_j + obs - 2 x_i.  16 threads/particle, 1024 blocks.
__global__ __launch_bounds__(256) void k_grad(const float* __restrict__ x,
                                              const float* __restrict__ apb,
                                              const float* __restrict__ obs,
                                              float* __restrict__ g) {
  int b   = blockIdx.x >> 7;          // 128 blocks/batch, 16 particles/block
  int ip  = threadIdx.x >> 4;
  int sub = threadIdx.x & 15;
  int i = (blockIdx.x & 127)*16 + ip;
  const float4* ab = (const float4*)apb + b*NPART;
  float4 xi = ((const float4*)x)[b*NPART + i];

  float sum1 = 0.f, sum2 = 0.f;
  float4 acc1 = make_float4(0.f,0.f,0.f,0.f);
  float4 acc2 = make_float4(0.f,0.f,0.f,0.f);
#pragma unroll 4
  for (int c = 0; c < 64; ++c) {
    int j = sub + 16*c;
    float4 a1 = ab[j];
    float4 a2 = ab[j + 1024];
    float dx1 = xi.x-a1.x, dy1 = xi.y-a1.y, dz1 = xi.z-a1.z, dw1 = xi.w-a1.w;
    float dx2 = xi.x-a2.x, dy2 = xi.y-a2.y, dz2 = xi.z-a2.z, dw2 = xi.w-a2.w;
    float e1 = __expf(-0.5f*(dx1*dx1 + dy1*dy1 + dz1*dz1 + dw1*dw1));
    float e2 = __expf(-0.5f*(dx2*dx2 + dy2*dy2 + dz2*dz2 + dw2*dw2));
    sum1 += e1; sum2 += e2;
    acc1.x += e1*a1.x; acc1.y += e1*a1.y; acc1.z += e1*a1.z; acc1.w += e1*a1.w;
    acc2.x += e2*a2.x; acc2.y += e2*a2.y; acc2.z += e2*a2.z; acc2.w += e2*a2.w;
  }
  float sum = sum1 + sum2;
  float4 acc = make_float4(acc1.x+acc2.x, acc1.y+acc2.y,
                           acc1.z+acc2.z, acc1.w+acc2.w);
#pragma unroll
  for (int d = 1; d < 16; d <<= 1) {
    sum   += __shfl_xor(sum, d);
    acc.x += __shfl_xor(acc.x, d);
    acc.y += __shfl_xor(acc.y, d);
    acc.z += __shfl_xor(acc.z, d);
    acc.w += __shfl_xor(acc.w, d);
  }
  if (sub == 0) {
    float inv = 1.0f / sum;
    float4 ob = ((const float4*)obs)[b];
    float4 gg;
    gg.x = acc.x*inv + ob.x - 2.0f*xi.x;
    gg.y = acc.y*inv + ob.y - 2.0f*xi.y;
    gg.z = acc.z*inv + ob.z - 2.0f*xi.z;
    gg.w = acc.w*inv + ob.w - 2.0f*xi.w;
    ((float4*)g)[b*NPART + i] = gg;
  }
}

// ---------- stein pass + RMSprop update, no LDS, 2-way ILP.
// stein_i = ( sum_j e_ij g_j + (2/h) sum_j e_ij (x_i - x_j) ) / N
// MODE 0: first iter.  MODE 1: middle.  MODE 2: last (writes (B,N,5) out).
template <int MODE>
__global__ __launch_bounds__(256) void k_stein(const float* __restrict__ x,
                                               const float* __restrict__ g,
                                               const float* __restrict__ hpar,
                                               float* __restrict__ stepb,
                                               float* __restrict__ xout,
                                               float* __restrict__ outp) {
  int b   = blockIdx.x >> 7;
  int ip  = threadIdx.x >> 4;
  int sub = threadIdx.x & 15;
  int i = (blockIdx.x & 127)*16 + ip;
  const float4* xb = (const float4*)x + b*NPART;
  const float4* gb = (const float4*)g + b*NPART;
  float neginvh = hpar[b*4 + 1];
  float two_h   = hpar[b*4 + 2];
  float4 xi = xb[i];

  float4 Sd1 = make_float4(0.f,0.f,0.f,0.f), Sd2 = Sd1;
  float4 Sg1 = Sd1, Sg2 = Sd1;
#pragma unroll 4
  for (int c = 0; c < 64; ++c) {
    int j = sub + 16*c;
    float4 xj1 = xb[j];
    float4 xj2 = xb[j + 1024];
    float4 gj1 = gb[j];
    float4 gj2 = gb[j + 1024];
    float dx1 = xi.x-xj1.x, dy1 = xi.y-xj1.y, dz1 = xi.z-xj1.z, dw1 = xi.w-xj1.w;
    float dx2 = xi.x-xj2.x, dy2 = xi.y-xj2.y, dz2 = xi.z-xj2.z, dw2 = xi.w-xj2.w;
    float e1 = __expf((dx1*dx1 + dy1*dy1 + dz1*dz1 + dw1*dw1) * neginvh);
    float e2 = __expf((dx2*dx2 + dy2*dy2 + dz2*dz2 + dw2*dw2) * neginvh);
    Sd1.x += e1*dx1; Sd1.y += e1*dy1; Sd1.z += e1*dz1; Sd1.w += e1*dw1;
    Sd2.x += e2*dx2; Sd2.y += e2*dy2; Sd2.z += e2*dz2; Sd2.w += e2*dw2;
    Sg1.x += e1*gj1.x; Sg1.y += e1*gj1.y; Sg1.z += e1*gj1.z; Sg1.w += e1*gj1.w;
    Sg2.x += e2*gj2.x; Sg2.y += e2*gj2.y; Sg2.z += e2*gj2.z; Sg2.w += e2*gj2.w;
  }
  float4 Sd = make_float4(Sd1.x+Sd2.x, Sd1.y+Sd2.y, Sd1.z+Sd2.z, Sd1.w+Sd2.w);
  float4 Sg = make_float4(Sg1.x+Sg2.x, Sg1.y+Sg2.y, Sg1.z+Sg2.z, Sg1.w+Sg2.w);
#pragma unroll
  for (int d = 1; d < 16; d <<= 1) {
    Sd.x += __shfl_xor(Sd.x, d); Sd.y += __shfl_xor(Sd.y, d);
    Sd.z += __shfl_xor(Sd.z, d); Sd.w += __shfl_xor(Sd.w, d);
    Sg.x += __shfl_xor(Sg.x, d); Sg.y += __shfl_xor(Sg.y, d);
    Sg.z += __shfl_xor(Sg.z, d); Sg.w += __shfl_xor(Sg.w, d);
  }
  if (sub == 0) {
    const float invN = 1.0f / 2048.0f;
    float4 sv;
    sv.x = (Sg.x + two_h*Sd.x) * invN;
    sv.y = (Sg.y + two_h*Sd.y) * invN;
    sv.z = (Sg.z + two_h*Sd.z) * invN;
    sv.w = (Sg.w + two_h*Sd.w) * invN;
    float4 st;
    if (MODE == 0) {
      st = make_float4(0.1f*sv.x*sv.x, 0.1f*sv.y*sv.y,
                       0.1f*sv.z*sv.z, 0.1f*sv.w*sv.w);
    } else {
      st = ((float4*)stepb)[b*NPART + i];
      st.x = 0.9f*st.x + 0.1f*sv.x*sv.x;
      st.y = 0.9f*st.y + 0.1f*sv.y*sv.y;
      st.z = 0.9f*st.z + 0.1f*sv.z*sv.z;
      st.w = 0.9f*st.w + 0.1f*sv.w*sv.w;
    }
    float4 xn;
    xn.x = xi.x + 0.1f*sv.x / (sqrtf(st.x) + 1e-8f);
    xn.y = xi.y + 0.1f*sv.y / (sqrtf(st.y) + 1e-8f);
    xn.z = xi.z + 0.1f*sv.z / (sqrtf(st.z) + 1e-8f);
    xn.w = xi.w + 0.1f*sv.w / (sqrtf(st.w) + 1e-8f);
    if (MODE != 2) {
      ((float4*)stepb)[b*NPART + i] = st;
      ((float4*)xout)[b*NPART + i] = xn;
    } else {
      float* o = outp + (size_t)(b*NPART + i) * 5;
      o[0] = xn.x; o[1] = xn.y; o[2] = xn.z; o[3] = xn.w;
      o[4] = -LOGN_F;
    }
  }
}

extern "C" void kernel_launch(void* const* d_in, const int* in_sizes, int n_in,
                              void* d_out, int out_size, void* d_ws, size_t ws_size,
                              hipStream_t stream) {
  const float* prev  = (const float*)d_in[0];   // (8,2048,4)
  const float* obs   = (const float*)d_in[1];   // (8,4)
  const float* noise = (const float*)d_in[2];   // (8,2048,4)
  float* out = (float*)d_out;                   // (8,2048,5)

  float* ws = (float*)d_ws;
  float* xA    = ws;
  float* xB    = xA + 65536;
  float* gbuf  = xB + 65536;
  float* stepb = gbuf + 65536;
  float* apb   = stepb + 65536;
  float* hpar  = apb + 65536;               // 32 floats
  int*   state = (int*)(hpar + 32);         // 32 ints
  int*   hist0 = state + 32;                // 8*2048 ints
  int*   hist1 = hist0 + 8*2048;            // 8*4096 ints (+pad to 65536)

  k_init<<<64, 256, 0, stream>>>(prev, noise, xA, apb, hist0);

  float* xc = xA;
  float* xn = xB;
  for (int it = 0; it < 3; ++it) {
    k_grad<<<1024, 256, 0, stream>>>(xc, apb, obs, gbuf);
    k_hist<0><<<1024, 256, 0, stream>>>(xc, state, hist0);
    k_scan0<<<8, 256, 0, stream>>>(hist0, state);
    k_hist<1><<<1024, 256, 0, stream>>>(xc, state, hist1);
    k_scan1<<<8, 256, 0, stream>>>(hist0, hist1, state, hpar);
    if (it == 0) {
      k_stein<0><<<1024, 256, 0, stream>>>(xc, gbuf, hpar, stepb, xn, nullptr);
    } else if (it == 1) {
      k_stein<1><<<1024, 256, 0, stream>>>(xc, gbuf, hpar, stepb, xn, nullptr);
    } else {
      k_stein<2><<<1024, 256, 0, stream>>>(xc, gbuf, hpar, stepb, nullptr, out);
    }
    float* t = xc; xc = xn; xn = t;
  }
}

// Round 6
// 359.488 us; speedup vs baseline: 2.0507x; 1.0628x over previous
//
#include <hip/hip_runtime.h>
#include <math.h>

// SVPF step: B=8, N=2048, D=4, fp32.  3 SVGD iterations.
// log_weight output channel is exactly -log(2048) (log_post cancels).
//
// R6 changes vs R5 (diagnosis: 19 graph launches x ~8-10us dispatch overhead
// ~= the 160us gap between kernel-work estimate and measured 382us):
//  - 10 launches: init + 3 x {S1 = grad||hist0, S2 = selfscan0+hist1,
//    S3 = selfscan1+stein}.  Scan kernels gone: each consumer block re-derives
//    the scan result from the (kernel-boundary-ordered) histogram.
//  - re-zeroing woven in: S1 zeroes hist1 (last read by prev S3), S3 zeroes
//    hist0 (last read by S2), init zeroes hist0 once.  No fences anywhere.
//  - hist0 uses 2 LDS histogram copies at stride 2049 (different banks for
//    the same bin) to halve hot-bin atomic serialization.
//  - stein: 2-row register tiling (rows i, i+16 share the xj/gj loads) ->
//    half the L1 traffic, VALU-bound.
//
// ws layout (floats):
//   xA[65536] xB[65536] g[65536] step[65536] ap[65536]
//   state[16 ints] hist0[8*2048 ints] hist1[8*4096 ints]

#define NPART 2048
#define KRANK 2097151               // (2048*2048-1)/2, lower-median rank
#define LOGN_F 7.6246189861593985f  // log(2048)
#define A_C 0.9f

// ---------- init: x0 = A*prev + noise; ap = A*prev; zero hist0
__global__ __launch_bounds__(256) void k_init(const float* __restrict__ prev,
                                              const float* __restrict__ noise,
                                              float* __restrict__ x0,
                                              float* __restrict__ apb,
                                              int* __restrict__ hist0) {
  int idx = blockIdx.x * 256 + threadIdx.x;   // 0..16383 (B*N)
  float4 p  = ((const float4*)prev)[idx];
  float4 nz = ((const float4*)noise)[idx];
  float4 ap = make_float4(A_C*p.x, A_C*p.y, A_C*p.z, A_C*p.w);
  ((float4*)x0)[idx]  = make_float4(ap.x+nz.x, ap.y+nz.y, ap.z+nz.z, ap.w+nz.w);
  ((float4*)apb)[idx] = ap;
  if (idx < 4096) ((int4*)hist0)[idx] = make_int4(0, 0, 0, 0);  // 16384 ints
}

// ---------- S1: blocks 0-1023 grad, 1024-2047 hist0.  Also zeroes hist1.
// grad: softmax over j of -0.5|x_i-ap_j|^2 (<=0, max-shift analytic);
//       g_i = sum_j w_ij ap_j + obs - 2 x_i.
// hist0: unordered pairs (i,(i+k)&2047), k=1..1024 (w=2; k==1024 w=1),
//        bins = float bits[30:20] of sq (2048 bins, 2 LDS copies).
__global__ __launch_bounds__(256) void k_s1(const float* __restrict__ x,
                                            const float* __restrict__ apb,
                                            const float* __restrict__ obs,
                                            float* __restrict__ g,
                                            int* __restrict__ hist0,
                                            int* __restrict__ hist1) {
  // zero hist1: 8192 int4 over 2048 blocks -> 4 int4 per block
  if (threadIdx.x < 4)
    ((int4*)hist1)[blockIdx.x*4 + threadIdx.x] = make_int4(0, 0, 0, 0);

  if (blockIdx.x < 1024) {
    // ---- grad ----
    int b   = blockIdx.x >> 7;        // 128 blocks/batch, 16 particles each
    int ip  = threadIdx.x >> 4;
    int sub = threadIdx.x & 15;
    int i = (blockIdx.x & 127)*16 + ip;
    const float4* ab = (const float4*)apb + b*NPART;
    float4 xi = ((const float4*)x)[b*NPART + i];

    float sum1 = 0.f, sum2 = 0.f;
    float4 acc1 = make_float4(0.f,0.f,0.f,0.f);
    float4 acc2 = make_float4(0.f,0.f,0.f,0.f);
#pragma unroll 4
    for (int c = 0; c < 64; ++c) {
      int j = sub + 16*c;
      float4 a1 = ab[j];
      float4 a2 = ab[j + 1024];
      float dx1 = xi.x-a1.x, dy1 = xi.y-a1.y, dz1 = xi.z-a1.z, dw1 = xi.w-a1.w;
      float dx2 = xi.x-a2.x, dy2 = xi.y-a2.y, dz2 = xi.z-a2.z, dw2 = xi.w-a2.w;
      float e1 = __expf(-0.5f*(dx1*dx1 + dy1*dy1 + dz1*dz1 + dw1*dw1));
      float e2 = __expf(-0.5f*(dx2*dx2 + dy2*dy2 + dz2*dz2 + dw2*dw2));
      sum1 += e1; sum2 += e2;
      acc1.x += e1*a1.x; acc1.y += e1*a1.y; acc1.z += e1*a1.z; acc1.w += e1*a1.w;
      acc2.x += e2*a2.x; acc2.y += e2*a2.y; acc2.z += e2*a2.z; acc2.w += e2*a2.w;
    }
    float sum = sum1 + sum2;
    float4 acc = make_float4(acc1.x+acc2.x, acc1.y+acc2.y,
                             acc1.z+acc2.z, acc1.w+acc2.w);
#pragma unroll
    for (int d = 1; d < 16; d <<= 1) {
      sum   += __shfl_xor(sum, d);
      acc.x += __shfl_xor(acc.x, d);
      acc.y += __shfl_xor(acc.y, d);
      acc.z += __shfl_xor(acc.z, d);
      acc.w += __shfl_xor(acc.w, d);
    }
    if (sub == 0) {
      float inv = 1.0f / sum;
      float4 ob = ((const float4*)obs)[b];
      float4 gg;
      gg.x = acc.x*inv + ob.x - 2.0f*xi.x;
      gg.y = acc.y*inv + ob.y - 2.0f*xi.y;
      gg.z = acc.z*inv + ob.z - 2.0f*xi.z;
      gg.w = acc.w*inv + ob.w - 2.0f*xi.w;
      ((float4*)g)[b*NPART + i] = gg;
    }
  } else {
    // ---- hist0 ----
    int bid   = blockIdx.x - 1024;
    int b     = bid >> 7;
    int sub2  = bid & 127;
    int itile = sub2 >> 4;            // 8 i-tiles of 256
    int ktile = sub2 & 15;            // 16 k-tiles of 64
    __shared__ float4 sxi[256];       // 4 KB
    __shared__ float4 sxw[320];       // 5 KB
    __shared__ int    sh[2*2049];     // 2 copies, bank-shifted (16 KB)

    const float4* xb = (const float4*)x + b*NPART;
    int ibase = itile*256;
    int k0 = ktile*64 + 1;
    sxi[threadIdx.x] = xb[ibase + threadIdx.x];
    for (int t = threadIdx.x; t < 320; t += 256)
      sxw[t] = xb[(ibase + k0 + t) & (NPART - 1)];
    for (int t = threadIdx.x; t < 2*2049; t += 256) sh[t] = 0;
    __syncthreads();

    float4 xi = sxi[threadIdx.x];
    int cofs = (threadIdx.x & 1) * 2049;
#pragma unroll 4
    for (int kk = 0; kk < 64; ++kk) {
      int w = (ktile == 15 && kk == 63) ? 1 : 2;   // wave-uniform
      float4 xj = sxw[threadIdx.x + kk];
      float dx = xi.x - xj.x, dy = xi.y - xj.y;
      float dz = xi.z - xj.z, dw = xi.w - xj.w;
      float sq = dx*dx + dy*dy + dz*dz + dw*dw;    // >= 0
      atomicAdd(&sh[cofs + (__float_as_uint(sq) >> 20)], w);
    }
    __syncthreads();
    int* hb = hist0 + b*2048;
    for (int t = threadIdx.x; t < 2048; t += 256) {
      int c = sh[t] + sh[t + 2049];
      if (c) atomicAdd(&hb[t], c);
    }
  }
}

// ---------- S2: self-scan of hist0 (phase-0 rank walk) + hist1 accumulation.
// Block (sub2==0) of each batch publishes {sel0, r0} to state.
__global__ __launch_bounds__(256) void k_s2(const float* __restrict__ x,
                                            int* __restrict__ state,
                                            const int* __restrict__ hist0,
                                            int* __restrict__ hist1) {
  int b     = blockIdx.x >> 7;
  int sub2  = blockIdx.x & 127;
  int itile = sub2 >> 4;
  int ktile = sub2 & 15;
  __shared__ float4 sxi[256];
  __shared__ float4 sxw[320];
  __shared__ int    sh[4096];
  __shared__ int    part[256];
  __shared__ int    s_sel0;

  const float4* xb = (const float4*)x + b*NPART;
  int ibase = itile*256;
  int k0 = ktile*64 + 1;
  sxi[threadIdx.x] = xb[ibase + threadIdx.x];
  for (int t = threadIdx.x; t < 320; t += 256)
    sxw[t] = xb[(ibase + k0 + t) & (NPART - 1)];
  for (int t = threadIdx.x; t < 4096; t += 256) sh[t] = 0;

  const int* h0 = hist0 + b*2048;
  int4 c0 = ((const int4*)h0)[threadIdx.x*2];
  int4 c1 = ((const int4*)h0)[threadIdx.x*2 + 1];
  int s = c0.x+c0.y+c0.z+c0.w + c1.x+c1.y+c1.z+c1.w;
  if (threadIdx.x == 0) s += NPART;   // diagonal zeros -> bin 0
  part[threadIdx.x] = s;
  __syncthreads();
  if (threadIdx.x == 0) {
    int r = KRANK, cum = 0, ch = 0;
    for (; ch < 256; ++ch) { if (cum + part[ch] > r) break; cum += part[ch]; }
    int4 d0 = ((const int4*)h0)[ch*2];
    int4 d1 = ((const int4*)h0)[ch*2 + 1];
    int cc[8] = {d0.x,d0.y,d0.z,d0.w,d1.x,d1.y,d1.z,d1.w};
    if (ch == 0) cc[0] += NPART;
    int q = 0;
    for (;; ++q) { if (cum + cc[q] > r) break; cum += cc[q]; }
    int bin = ch*8 + q;
    s_sel0 = bin;
    if (sub2 == 0) { state[b*2] = bin; state[b*2 + 1] = r - cum; }
  }
  __syncthreads();
  int sel0 = s_sel0;

  float4 xi = sxi[threadIdx.x];
#pragma unroll 4
  for (int kk = 0; kk < 64; ++kk) {
    int w = (ktile == 15 && kk == 63) ? 1 : 2;
    float4 xj = sxw[threadIdx.x + kk];
    float dx = xi.x - xj.x, dy = xi.y - xj.y;
    float dz = xi.z - xj.z, dw = xi.w - xj.w;
    float sq = dx*dx + dy*dy + dz*dz + dw*dw;
    unsigned bits = __float_as_uint(sq);
    if ((int)(bits >> 20) == sel0) atomicAdd(&sh[(bits >> 8) & 4095], w);
  }
  __syncthreads();
  int* hb = hist1 + b*4096;
  for (int t = threadIdx.x; t < 4096; t += 256) {
    int c = sh[t];
    if (c) atomicAdd(&hb[t], c);
  }
}

// ---------- S3: zero hist0; self-scan of hist1 -> h; stein + RMSprop.
// 512 blocks, 32 particles/block, 2-row register tiling (rows ip, ip+16).
// MODE 0: first iter.  MODE 1: middle.  MODE 2: last (writes (B,N,5) out).
template <int MODE>
__global__ __launch_bounds__(256) void k_s3(const float* __restrict__ x,
                                            const float* __restrict__ g,
                                            const int* __restrict__ state,
                                            int* __restrict__ hist0,
                                            const int* __restrict__ hist1,
                                            float* __restrict__ stepb,
                                            float* __restrict__ xout,
                                            float* __restrict__ outp) {
  // zero hist0: 4096 int4 over 512 blocks -> 8 int4 per block
  // (safe: hist0's last reader was S2, a previous kernel)
  if (threadIdx.x < 8)
    ((int4*)hist0)[blockIdx.x*8 + threadIdx.x] = make_int4(0, 0, 0, 0);

  int b   = blockIdx.x >> 6;          // 64 blocks/batch
  int blk = blockIdx.x & 63;
  __shared__ int   part[256];
  __shared__ float shp[2];            // -1/h, 2/h

  const int* h1 = hist1 + b*4096;
  int4 c0 = ((const int4*)h1)[threadIdx.x*4 + 0];
  int4 c1 = ((const int4*)h1)[threadIdx.x*4 + 1];
  int4 c2 = ((const int4*)h1)[threadIdx.x*4 + 2];
  int4 c3 = ((const int4*)h1)[threadIdx.x*4 + 3];
  int s = c0.x+c0.y+c0.z+c0.w + c1.x+c1.y+c1.z+c1.w
        + c2.x+c2.y+c2.z+c2.w + c3.x+c3.y+c3.z+c3.w;
  int sel0 = state[b*2];
  if (threadIdx.x == 0 && sel0 == 0) s += NPART;
  part[threadIdx.x] = s;
  __syncthreads();
  if (threadIdx.x == 0) {
    int r = state[b*2 + 1], cum = 0, ch = 0;
    for (; ch < 256; ++ch) { if (cum + part[ch] > r) break; cum += part[ch]; }
    int4 d0 = ((const int4*)h1)[ch*4 + 0];
    int4 d1 = ((const int4*)h1)[ch*4 + 1];
    int4 d2 = ((const int4*)h1)[ch*4 + 2];
    int4 d3 = ((const int4*)h1)[ch*4 + 3];
    int cc[16] = {d0.x,d0.y,d0.z,d0.w, d1.x,d1.y,d1.z,d1.w,
                  d2.x,d2.y,d2.z,d2.w, d3.x,d3.y,d3.z,d3.w};
    if (sel0 == 0 && ch == 0) cc[0] += NPART;
    int q = 0;
    for (;; ++q) { if (cum + cc[q] > r) break; cum += cc[q]; }
    int bin = ch*16 + q;
    // top 24 bits exact; low 8 -> midpoint (rel err <= 2^-16)
    unsigned mb = (((unsigned)sel0) << 20) | (((unsigned)bin) << 8) | 128u;
    float med = sqrtf(__uint_as_float(mb));
    float h = med * med / LOGN_F;
    shp[0] = -1.0f / h;
    shp[1] =  2.0f / h;
  }
  __syncthreads();
  float neginvh = shp[0];
  float two_h   = shp[1];

  int ip  = threadIdx.x >> 4;
  int sub = threadIdx.x & 15;
  int rowA = blk*32 + ip;
  int rowB = rowA + 16;
  const float4* xb = (const float4*)x + b*NPART;
  const float4* gb = (const float4*)g + b*NPART;
  float4 xiA = xb[rowA];
  float4 xiB = xb[rowB];

  float4 SdA = make_float4(0.f,0.f,0.f,0.f), SgA = SdA;
  float4 SdB = SdA, SgB = SdA;
#pragma unroll 4
  for (int c = 0; c < 128; ++c) {
    int j = sub + 16*c;
    float4 xj = xb[j];
    float4 gj = gb[j];
    float dxA = xiA.x-xj.x, dyA = xiA.y-xj.y, dzA = xiA.z-xj.z, dwA = xiA.w-xj.w;
    float dxB = xiB.x-xj.x, dyB = xiB.y-xj.y, dzB = xiB.z-xj.z, dwB = xiB.w-xj.w;
    float eA = __expf((dxA*dxA + dyA*dyA + dzA*dzA + dwA*dwA) * neginvh);
    float eB = __expf((dxB*dxB + dyB*dyB + dzB*dzB + dwB*dwB) * neginvh);
    SdA.x += eA*dxA; SdA.y += eA*dyA; SdA.z += eA*dzA; SdA.w += eA*dwA;
    SdB.x += eB*dxB; SdB.y += eB*dyB; SdB.z += eB*dzB; SdB.w += eB*dwB;
    SgA.x += eA*gj.x; SgA.y += eA*gj.y; SgA.z += eA*gj.z; SgA.w += eA*gj.w;
    SgB.x += eB*gj.x; SgB.y += eB*gj.y; SgB.z += eB*gj.z; SgB.w += eB*gj.w;
  }
#pragma unroll
  for (int d = 1; d < 16; d <<= 1) {
    SdA.x += __shfl_xor(SdA.x, d); SdA.y += __shfl_xor(SdA.y, d);
    SdA.z += __shfl_xor(SdA.z, d); SdA.w += __shfl_xor(SdA.w, d);
    SgA.x += __shfl_xor(SgA.x, d); SgA.y += __shfl_xor(SgA.y, d);
    SgA.z += __shfl_xor(SgA.z, d); SgA.w += __shfl_xor(SgA.w, d);
    SdB.x += __shfl_xor(SdB.x, d); SdB.y += __shfl_xor(SdB.y, d);
    SdB.z += __shfl_xor(SdB.z, d); SdB.w += __shfl_xor(SdB.w, d);
    SgB.x += __shfl_xor(SgB.x, d); SgB.y += __shfl_xor(SgB.y, d);
    SgB.z += __shfl_xor(SgB.z, d); SgB.w += __shfl_xor(SgB.w, d);
  }
  if (sub == 0) {
    const float invN = 1.0f / 2048.0f;
#pragma unroll
    for (int rr = 0; rr < 2; ++rr) {
      int row = rr ? rowB : rowA;
      float4 xi = rr ? xiB : xiA;
      float4 Sd = rr ? SdB : SdA;
      float4 Sg = rr ? SgB : SgA;
      float4 sv;
      sv.x = (Sg.x + two_h*Sd.x) * invN;
      sv.y = (Sg.y + two_h*Sd.y) * invN;
      sv.z = (Sg.z + two_h*Sd.z) * invN;
      sv.w = (Sg.w + two_h*Sd.w) * invN;
      float4 st;
      if (MODE == 0) {
        st = make_float4(0.1f*sv.x*sv.x, 0.1f*sv.y*sv.y,
                         0.1f*sv.z*sv.z, 0.1f*sv.w*sv.w);
      } else {
        st = ((float4*)stepb)[b*NPART + row];
        st.x = 0.9f*st.x + 0.1f*sv.x*sv.x;
        st.y = 0.9f*st.y + 0.1f*sv.y*sv.y;
        st.z = 0.9f*st.z + 0.1f*sv.z*sv.z;
        st.w = 0.9f*st.w + 0.1f*sv.w*sv.w;
      }
      float4 xn;
      xn.x = xi.x + 0.1f*sv.x / (sqrtf(st.x) + 1e-8f);
      xn.y = xi.y + 0.1f*sv.y / (sqrtf(st.y) + 1e-8f);
      xn.z = xi.z + 0.1f*sv.z / (sqrtf(st.z) + 1e-8f);
      xn.w = xi.w + 0.1f*sv.w / (sqrtf(st.w) + 1e-8f);
      if (MODE != 2) {
        ((float4*)stepb)[b*NPART + row] = st;
        ((float4*)xout)[b*NPART + row] = xn;
      } else {
        float* o = outp + (size_t)(b*NPART + row) * 5;
        o[0] = xn.x; o[1] = xn.y; o[2] = xn.z; o[3] = xn.w;
        o[4] = -LOGN_F;
      }
    }
  }
}

extern "C" void kernel_launch(void* const* d_in, const int* in_sizes, int n_in,
                              void* d_out, int out_size, void* d_ws, size_t ws_size,
                              hipStream_t stream) {
  const float* prev  = (const float*)d_in[0];   // (8,2048,4)
  const float* obs   = (const float*)d_in[1];   // (8,4)
  const float* noise = (const float*)d_in[2];   // (8,2048,4)
  float* out = (float*)d_out;                   // (8,2048,5)

  float* ws = (float*)d_ws;
  float* xA    = ws;
  float* xB    = xA + 65536;
  float* gbuf  = xB + 65536;
  float* stepb = gbuf + 65536;
  float* apb   = stepb + 65536;
  int*   state = (int*)(apb + 65536);       // 16 ints
  int*   hist0 = state + 16;                // 8*2048 ints
  int*   hist1 = hist0 + 8*2048;            // 8*4096 ints

  k_init<<<64, 256, 0, stream>>>(prev, noise, xA, apb, hist0);

  float* xc = xA;
  float* xn = xB;
  for (int it = 0; it < 3; ++it) {
    k_s1<<<2048, 256, 0, stream>>>(xc, apb, obs, gbuf, hist0, hist1);
    k_s2<<<1024, 256, 0, stream>>>(xc, state, hist0, hist1);
    if (it == 0) {
      k_s3<0><<<512, 256, 0, stream>>>(xc, gbuf, state, hist0, hist1, stepb, xn, nullptr);
    } else if (it == 1) {
      k_s3<1><<<512, 256, 0, stream>>>(xc, gbuf, state, hist0, hist1, stepb, xn, nullptr);
    } else {
      k_s3<2><<<512, 256, 0, stream>>>(xc, gbuf, state, hist0, hist1, stepb, nullptr, out);
    }
    float* t = xc; xc = xn; xn = t;
  }
}

// Round 7
// 328.334 us; speedup vs baseline: 2.2453x; 1.0949x over previous
//
#include <hip/hip_runtime.h>
#include <math.h>

// SVPF step: B=8, N=2048, D=4, fp32.  3 SVGD iterations.
// log_weight output channel is exactly -log(2048) (log_post cancels).
//
// R7 changes vs R6 (diagnosis: k_s3 60us = 181us total; VGPR=32 shows the
// compiler kept NO loads in flight, and 512 blocks = 2 waves/SIMD killed
// latency hiding; j-stream re-read per 16-lane group = ~1GB of L1 traffic):
//  - grad & stein: L=64 lanes/group, R=4 rows/group -> 1024 blocks (4/CU,
//    4 waves/SIMD) AND 4x less j-traffic.  Loads batched into NAMED vars
//    (A..D) to force in-flight loads (R5 evidence: manual ILP pipelines,
//    pragma-only does not).  __launch_bounds__(256,4) caps VGPR at 128.
//  - stein algebra: c_j = g_j - (2/h) x_j shared across rows;
//    stein_i = (sum_j e_ij c_j + (2/h) S0_i x_i)/N  (15 ops/pair).
//  - S1 interleaves grad/hist block roles via blockIdx&1 (CU mix).
//  - hist/scan structure unchanged from R6 (not the bottleneck).
//
// ws layout (floats):
//   xA[65536] xB[65536] g[65536] step[65536] ap[65536]
//   state[16 ints] hist0[8*2048 ints] hist1[8*4096 ints]

#define NPART 2048
#define KRANK 2097151               // (2048*2048-1)/2, lower-median rank
#define LOGN_F 7.6246189861593985f  // log(2048)
#define A_C 0.9f

// ---------- init: x0 = A*prev + noise; ap = A*prev; zero hist0+hist1
__global__ __launch_bounds__(256) void k_init(const float* __restrict__ prev,
                                              const float* __restrict__ noise,
                                              float* __restrict__ x0,
                                              float* __restrict__ apb,
                                              int* __restrict__ hists) {
  int idx = blockIdx.x * 256 + threadIdx.x;   // 0..16383 (B*N)
  float4 p  = ((const float4*)prev)[idx];
  float4 nz = ((const float4*)noise)[idx];
  float4 ap = make_float4(A_C*p.x, A_C*p.y, A_C*p.z, A_C*p.w);
  ((float4*)x0)[idx]  = make_float4(ap.x+nz.x, ap.y+nz.y, ap.z+nz.z, ap.w+nz.w);
  ((float4*)apb)[idx] = ap;
  if (idx < 12288) ((int4*)hists)[idx] = make_int4(0, 0, 0, 0);  // 49152 ints
}

// ---- per-pair helpers (all register, compile-time indexed) ----
__device__ __forceinline__ void grad_j(const float4* xi, const float4 ap,
                                       float* s, float4* acc) {
#pragma unroll
  for (int r = 0; r < 4; ++r) {
    float dx = xi[r].x - ap.x, dy = xi[r].y - ap.y;
    float dz = xi[r].z - ap.z, dw = xi[r].w - ap.w;
    float sq = fmaf(dx, dx, fmaf(dy, dy, fmaf(dz, dz, dw*dw)));
    float e = __expf(-0.5f * sq);
    s[r] += e;
    acc[r].x = fmaf(e, ap.x, acc[r].x);
    acc[r].y = fmaf(e, ap.y, acc[r].y);
    acc[r].z = fmaf(e, ap.z, acc[r].z);
    acc[r].w = fmaf(e, ap.w, acc[r].w);
  }
}

__device__ __forceinline__ void stein_j(const float4* xi, const float4 xj,
                                        const float4 gj, float two_h,
                                        float ninvh, float* s0, float4* sc) {
  float4 cj;   // g_j - (2/h) x_j, shared across the 4 rows
  cj.x = fmaf(-two_h, xj.x, gj.x);
  cj.y = fmaf(-two_h, xj.y, gj.y);
  cj.z = fmaf(-two_h, xj.z, gj.z);
  cj.w = fmaf(-two_h, xj.w, gj.w);
#pragma unroll
  for (int r = 0; r < 4; ++r) {
    float dx = xi[r].x - xj.x, dy = xi[r].y - xj.y;
    float dz = xi[r].z - xj.z, dw = xi[r].w - xj.w;
    float sq = fmaf(dx, dx, fmaf(dy, dy, fmaf(dz, dz, dw*dw)));
    float e = __expf(sq * ninvh);
    s0[r] += e;
    sc[r].x = fmaf(e, cj.x, sc[r].x);
    sc[r].y = fmaf(e, cj.y, sc[r].y);
    sc[r].z = fmaf(e, cj.z, sc[r].z);
    sc[r].w = fmaf(e, cj.w, sc[r].w);
  }
}

// ---------- S1: role = blockIdx&1.  role 0: grad (1024 blocks, 16 rows ea).
// role 1: hist0 (1024 blocks, R6 structure).  Also zeroes hist1.
__global__ __launch_bounds__(256, 4) void k_s1(const float* __restrict__ x,
                                               const float* __restrict__ apb,
                                               const float* __restrict__ obs,
                                               float* __restrict__ g,
                                               int* __restrict__ hist0,
                                               int* __restrict__ hist1) {
  if (threadIdx.x < 4)
    ((int4*)hist1)[blockIdx.x*4 + threadIdx.x] = make_int4(0, 0, 0, 0);
  int role = blockIdx.x & 1;
  int id   = blockIdx.x >> 1;

  if (role == 0) {
    // ---- grad: wave (64 lanes) serves 4 rows; block = 16 rows ----
    int b = id >> 7;                        // 128 blocks/batch
    int rbase = (id & 127)*16 + (threadIdx.x >> 6)*4;
    int lane = threadIdx.x & 63;
    const float4* xb = (const float4*)x + b*NPART;
    const float4* ab = (const float4*)apb + b*NPART;
    float4 xi[4];
#pragma unroll
    for (int r = 0; r < 4; ++r) xi[r] = xb[rbase + r];
    float  sum[4] = {0.f, 0.f, 0.f, 0.f};
    float4 acc[4] = {{0,0,0,0},{0,0,0,0},{0,0,0,0},{0,0,0,0}};

    for (int c = 0; c < 2048; c += 256) {
      int j = lane + c;
      float4 aA = ab[j];
      float4 aB = ab[j + 64];
      float4 aC = ab[j + 128];
      float4 aD = ab[j + 192];
      grad_j(xi, aA, sum, acc);
      grad_j(xi, aB, sum, acc);
      grad_j(xi, aC, sum, acc);
      grad_j(xi, aD, sum, acc);
    }
#pragma unroll
    for (int d = 1; d < 64; d <<= 1) {
#pragma unroll
      for (int r = 0; r < 4; ++r) {
        sum[r]   += __shfl_xor(sum[r], d);
        acc[r].x += __shfl_xor(acc[r].x, d);
        acc[r].y += __shfl_xor(acc[r].y, d);
        acc[r].z += __shfl_xor(acc[r].z, d);
        acc[r].w += __shfl_xor(acc[r].w, d);
      }
    }
    if (lane == 0) {
      float4 ob = ((const float4*)obs)[b];
#pragma unroll
      for (int r = 0; r < 4; ++r) {
        float inv = 1.0f / sum[r];
        float4 gg;
        gg.x = fmaf(acc[r].x, inv, fmaf(-2.0f, xi[r].x, ob.x));
        gg.y = fmaf(acc[r].y, inv, fmaf(-2.0f, xi[r].y, ob.y));
        gg.z = fmaf(acc[r].z, inv, fmaf(-2.0f, xi[r].z, ob.z));
        gg.w = fmaf(acc[r].w, inv, fmaf(-2.0f, xi[r].w, ob.w));
        ((float4*)g)[b*NPART + rbase + r] = gg;
      }
    }
  } else {
    // ---- hist0 (R6 structure): LDS-staged, 2-copy histogram ----
    int b     = id >> 7;
    int sub2  = id & 127;
    int itile = sub2 >> 4;            // 8 i-tiles of 256
    int ktile = sub2 & 15;            // 16 k-tiles of 64
    __shared__ float4 sxi[256];
    __shared__ float4 sxw[320];
    __shared__ int    sh[2*2049];

    const float4* xb = (const float4*)x + b*NPART;
    int ibase = itile*256;
    int k0 = ktile*64 + 1;
    sxi[threadIdx.x] = xb[ibase + threadIdx.x];
    for (int t = threadIdx.x; t < 320; t += 256)
      sxw[t] = xb[(ibase + k0 + t) & (NPART - 1)];
    for (int t = threadIdx.x; t < 2*2049; t += 256) sh[t] = 0;
    __syncthreads();

    float4 xi = sxi[threadIdx.x];
    int cofs = (threadIdx.x & 1) * 2049;
#pragma unroll 4
    for (int kk = 0; kk < 64; ++kk) {
      int w = (ktile == 15 && kk == 63) ? 1 : 2;   // wave-uniform
      float4 xj = sxw[threadIdx.x + kk];
      float dx = xi.x - xj.x, dy = xi.y - xj.y;
      float dz = xi.z - xj.z, dw = xi.w - xj.w;
      float sq = dx*dx + dy*dy + dz*dz + dw*dw;    // >= 0
      atomicAdd(&sh[cofs + (__float_as_uint(sq) >> 20)], w);
    }
    __syncthreads();
    int* hb = hist0 + b*2048;
    for (int t = threadIdx.x; t < 2048; t += 256) {
      int c = sh[t] + sh[t + 2049];
      if (c) atomicAdd(&hb[t], c);
    }
  }
}

// ---------- S2: self-scan of hist0 (phase-0 rank walk) + hist1 accumulation.
// Block (sub2==0) of each batch publishes {sel0, r0} to state.
__global__ __launch_bounds__(256) void k_s2(const float* __restrict__ x,
                                            int* __restrict__ state,
                                            const int* __restrict__ hist0,
                                            int* __restrict__ hist1) {
  int b     = blockIdx.x >> 7;
  int sub2  = blockIdx.x & 127;
  int itile = sub2 >> 4;
  int ktile = sub2 & 15;
  __shared__ float4 sxi[256];
  __shared__ float4 sxw[320];
  __shared__ int    sh[4096];
  __shared__ int    part[256];
  __shared__ int    s_sel0;

  const float4* xb = (const float4*)x + b*NPART;
  int ibase = itile*256;
  int k0 = ktile*64 + 1;
  sxi[threadIdx.x] = xb[ibase + threadIdx.x];
  for (int t = threadIdx.x; t < 320; t += 256)
    sxw[t] = xb[(ibase + k0 + t) & (NPART - 1)];
  for (int t = threadIdx.x; t < 4096; t += 256) sh[t] = 0;

  const int* h0 = hist0 + b*2048;
  int4 c0 = ((const int4*)h0)[threadIdx.x*2];
  int4 c1 = ((const int4*)h0)[threadIdx.x*2 + 1];
  int s = c0.x+c0.y+c0.z+c0.w + c1.x+c1.y+c1.z+c1.w;
  if (threadIdx.x == 0) s += NPART;   // diagonal zeros -> bin 0
  part[threadIdx.x] = s;
  __syncthreads();
  if (threadIdx.x == 0) {
    int r = KRANK, cum = 0, ch = 0;
    for (; ch < 256; ++ch) { if (cum + part[ch] > r) break; cum += part[ch]; }
    int4 d0 = ((const int4*)h0)[ch*2];
    int4 d1 = ((const int4*)h0)[ch*2 + 1];
    int cc[8] = {d0.x,d0.y,d0.z,d0.w,d1.x,d1.y,d1.z,d1.w};
    if (ch == 0) cc[0] += NPART;
    int q = 0;
    for (;; ++q) { if (cum + cc[q] > r) break; cum += cc[q]; }
    int bin = ch*8 + q;
    s_sel0 = bin;
    if (sub2 == 0) { state[b*2] = bin; state[b*2 + 1] = r - cum; }
  }
  __syncthreads();
  int sel0 = s_sel0;

  float4 xi = sxi[threadIdx.x];
#pragma unroll 4
  for (int kk = 0; kk < 64; ++kk) {
    int w = (ktile == 15 && kk == 63) ? 1 : 2;
    float4 xj = sxw[threadIdx.x + kk];
    float dx = xi.x - xj.x, dy = xi.y - xj.y;
    float dz = xi.z - xj.z, dw = xi.w - xj.w;
    float sq = dx*dx + dy*dy + dz*dz + dw*dw;
    unsigned bits = __float_as_uint(sq);
    if ((int)(bits >> 20) == sel0) atomicAdd(&sh[(bits >> 8) & 4095], w);
  }
  __syncthreads();
  int* hb = hist1 + b*4096;
  for (int t = threadIdx.x; t < 4096; t += 256) {
    int c = sh[t];
    if (c) atomicAdd(&hb[t], c);
  }
}

// ---------- S3: zero hist0; self-scan hist1 -> h; stein + RMSprop.
// 1024 blocks, 16 rows each; wave (64 lanes) serves 4 rows.
// MODE 0: first iter.  MODE 1: middle.  MODE 2: last (writes (B,N,5) out).
template <int MODE>
__global__ __launch_bounds__(256, 4) void k_s3(const float* __restrict__ x,
                                               const float* __restrict__ g,
                                               const int* __restrict__ state,
                                               int* __restrict__ hist0,
                                               const int* __restrict__ hist1,
                                               float* __restrict__ stepb,
                                               float* __restrict__ xout,
                                               float* __restrict__ outp) {
  // zero hist0 (last read by S2, a previous kernel)
  if (threadIdx.x < 4)
    ((int4*)hist0)[blockIdx.x*4 + threadIdx.x] = make_int4(0, 0, 0, 0);

  int b = blockIdx.x >> 7;            // 128 blocks/batch
  __shared__ int   part[256];
  __shared__ float shp[2];            // -1/h, 2/h

  const int* h1 = hist1 + b*4096;
  int4 c0 = ((const int4*)h1)[threadIdx.x*4 + 0];
  int4 c1 = ((const int4*)h1)[threadIdx.x*4 + 1];
  int4 c2 = ((const int4*)h1)[threadIdx.x*4 + 2];
  int4 c3 = ((const int4*)h1)[threadIdx.x*4 + 3];
  int s = c0.x+c0.y+c0.z+c0.w + c1.x+c1.y+c1.z+c1.w
        + c2.x+c2.y+c2.z+c2.w + c3.x+c3.y+c3.z+c3.w;
  int sel0 = state[b*2];
  if (threadIdx.x == 0 && sel0 == 0) s += NPART;
  part[threadIdx.x] = s;
  __syncthreads();
  if (threadIdx.x == 0) {
    int r = state[b*2 + 1], cum = 0, ch = 0;
    for (; ch < 256; ++ch) { if (cum + part[ch] > r) break; cum += part[ch]; }
    int4 d0 = ((const int4*)h1)[ch*4 + 0];
    int4 d1 = ((const int4*)h1)[ch*4 + 1];
    int4 d2 = ((const int4*)h1)[ch*4 + 2];
    int4 d3 = ((const int4*)h1)[ch*4 + 3];
    int cc[16] = {d0.x,d0.y,d0.z,d0.w, d1.x,d1.y,d1.z,d1.w,
                  d2.x,d2.y,d2.z,d2.w, d3.x,d3.y,d3.z,d3.w};
    if (sel0 == 0 && ch == 0) cc[0] += NPART;
    int q = 0;
    for (;; ++q) { if (cum + cc[q] > r) break; cum += cc[q]; }
    int bin = ch*16 + q;
    // top 24 bits exact; low 8 -> midpoint (rel err <= 2^-16)
    unsigned mb = (((unsigned)sel0) << 20) | (((unsigned)bin) << 8) | 128u;
    float med = sqrtf(__uint_as_float(mb));
    float h = med * med / LOGN_F;
    shp[0] = -1.0f / h;
    shp[1] =  2.0f / h;
  }
  __syncthreads();
  float neginvh = shp[0];
  float two_h   = shp[1];

  int rbase = (blockIdx.x & 127)*16 + (threadIdx.x >> 6)*4;
  int lane = threadIdx.x & 63;
  const float4* xb = (const float4*)x + b*NPART;
  const float4* gb = (const float4*)g + b*NPART;
  float4 xi[4];
#pragma unroll
  for (int r = 0; r < 4; ++r) xi[r] = xb[rbase + r];
  float  S0[4] = {0.f, 0.f, 0.f, 0.f};
  float4 Sc[4] = {{0,0,0,0},{0,0,0,0},{0,0,0,0},{0,0,0,0}};

  for (int c = 0; c < 2048; c += 256) {
    int j = lane + c;
    float4 xjA = xb[j];        float4 gjA = gb[j];
    float4 xjB = xb[j + 64];   float4 gjB = gb[j + 64];
    float4 xjC = xb[j + 128];  float4 gjC = gb[j + 128];
    float4 xjD = xb[j + 192];  float4 gjD = gb[j + 192];
    stein_j(xi, xjA, gjA, two_h, neginvh, S0, Sc);
    stein_j(xi, xjB, gjB, two_h, neginvh, S0, Sc);
    stein_j(xi, xjC, gjC, two_h, neginvh, S0, Sc);
    stein_j(xi, xjD, gjD, two_h, neginvh, S0, Sc);
  }
#pragma unroll
  for (int d = 1; d < 64; d <<= 1) {
#pragma unroll
    for (int r = 0; r < 4; ++r) {
      S0[r]   += __shfl_xor(S0[r], d);
      Sc[r].x += __shfl_xor(Sc[r].x, d);
      Sc[r].y += __shfl_xor(Sc[r].y, d);
      Sc[r].z += __shfl_xor(Sc[r].z, d);
      Sc[r].w += __shfl_xor(Sc[r].w, d);
    }
  }
  if (lane == 0) {
    const float invN = 1.0f / 2048.0f;
#pragma unroll
    for (int r = 0; r < 4; ++r) {
      int row = rbase + r;
      float th0 = two_h * S0[r];
      float4 sv;
      sv.x = fmaf(th0, xi[r].x, Sc[r].x) * invN;
      sv.y = fmaf(th0, xi[r].y, Sc[r].y) * invN;
      sv.z = fmaf(th0, xi[r].z, Sc[r].z) * invN;
      sv.w = fmaf(th0, xi[r].w, Sc[r].w) * invN;
      float4 st;
      if (MODE == 0) {
        st = make_float4(0.1f*sv.x*sv.x, 0.1f*sv.y*sv.y,
                         0.1f*sv.z*sv.z, 0.1f*sv.w*sv.w);
      } else {
        st = ((float4*)stepb)[b*NPART + row];
        st.x = 0.9f*st.x + 0.1f*sv.x*sv.x;
        st.y = 0.9f*st.y + 0.1f*sv.y*sv.y;
        st.z = 0.9f*st.z + 0.1f*sv.z*sv.z;
        st.w = 0.9f*st.w + 0.1f*sv.w*sv.w;
      }
      float4 xn;
      xn.x = xi[r].x + 0.1f*sv.x / (sqrtf(st.x) + 1e-8f);
      xn.y = xi[r].y + 0.1f*sv.y / (sqrtf(st.y) + 1e-8f);
      xn.z = xi[r].z + 0.1f*sv.z / (sqrtf(st.z) + 1e-8f);
      xn.w = xi[r].w + 0.1f*sv.w / (sqrtf(st.w) + 1e-8f);
      if (MODE != 2) {
        ((float4*)stepb)[b*NPART + row] = st;
        ((float4*)xout)[b*NPART + row] = xn;
      } else {
        float* o = outp + (size_t)(b*NPART + row) * 5;
        o[0] = xn.x; o[1] = xn.y; o[2] = xn.z; o[3] = xn.w;
        o[4] = -LOGN_F;
      }
    }
  }
}

extern "C" void kernel_launch(void* const* d_in, const int* in_sizes, int n_in,
                              void* d_out, int out_size, void* d_ws, size_t ws_size,
                              hipStream_t stream) {
  const float* prev  = (const float*)d_in[0];   // (8,2048,4)
  const float* obs   = (const float*)d_in[1];   // (8,4)
  const float* noise = (const float*)d_in[2];   // (8,2048,4)
  float* out = (float*)d_out;                   // (8,2048,5)

  float* ws = (float*)d_ws;
  float* xA    = ws;
  float* xB    = xA + 65536;
  float* gbuf  = xB + 65536;
  float* stepb = gbuf + 65536;
  float* apb   = stepb + 65536;
  int*   state = (int*)(apb + 65536);       // 16 ints
  int*   hist0 = state + 16;                // 8*2048 ints
  int*   hist1 = hist0 + 8*2048;            // 8*4096 ints

  k_init<<<64, 256, 0, stream>>>(prev, noise, xA, apb, hist0);

  float* xc = xA;
  float* xn = xB;
  for (int it = 0; it < 3; ++it) {
    k_s1<<<2048, 256, 0, stream>>>(xc, apb, obs, gbuf, hist0, hist1);
    k_s2<<<1024, 256, 0, stream>>>(xc, state, hist0, hist1);
    if (it == 0) {
      k_s3<0><<<1024, 256, 0, stream>>>(xc, gbuf, state, hist0, hist1, stepb, xn, nullptr);
    } else if (it == 1) {
      k_s3<1><<<1024, 256, 0, stream>>>(xc, gbuf, state, hist0, hist1, stepb, xn, nullptr);
    } else {
      k_s3<2><<<1024, 256, 0, stream>>>(xc, gbuf, state, hist0, hist1, stepb, nullptr, out);
    }
    float* t = xc; xc = xn; xn = t;
  }
}